// Round 1
// baseline (32000.638 us; speedup 1.0000x reference)
//
#include <hip/hip_runtime.h>
#include <hip/hip_bf16.h>

// Problem constants
#define BSZ   8
#define SEQL  2048
#define HID   1024
#define HH    512
#define NSP   32
#define NHEAD 16
#define HDIM  64

__device__ __forceinline__ float bf2f(unsigned short u) {
    unsigned int x = ((unsigned int)u) << 16;
    return __uint_as_float(x);
}
__device__ __forceinline__ unsigned short f2bf(float f) {
    unsigned int x = __float_as_uint(f);
    unsigned int r = (x + 0x7fffu + ((x >> 16) & 1u)) >> 16;
    return (unsigned short)r;
}

// ---------------------------------------------------------------------------
// Generic tiled f32 GEMM: C[row,col] = sum_k X[row,k] * W(k,col) + bias[col]
// TB=1: W is [N,K] (use W[col][k])   TB=0: W is [K,N]
// PERM=1: output index permuted for LSTM pre layout [t][b][m] (row = b*2048+t)
// OUTBF16=1: store bf16, else f32.
// Tiles 128x128, BK=16, 256 threads, 8x8 per thread.
// ---------------------------------------------------------------------------
template<int TB, int OUTBF16, int PERM>
__global__ __launch_bounds__(256)
void gemm_f32(const float* __restrict__ X, const float* __restrict__ W,
              const float* __restrict__ bias, void* __restrict__ out,
              int M, int N, int K)
{
    __shared__ float a_s[16][132];
    __shared__ float b_s[16][132];
    const int tid = threadIdx.x;
    const int n0 = blockIdx.x * 128;
    const int m0 = blockIdx.y * 128;
    const int tx = tid & 15, ty = tid >> 4;
    float acc[8][8];
#pragma unroll
    for (int i = 0; i < 8; i++)
#pragma unroll
        for (int j = 0; j < 8; j++) acc[i][j] = 0.f;

    for (int k0 = 0; k0 < K; k0 += 16) {
#pragma unroll
        for (int i = 0; i < 2; i++) {
            int f4 = tid + 256 * i;
            int row = f4 >> 2, kc = f4 & 3;
            float4 v = *(const float4*)(X + (size_t)(m0 + row) * K + (k0 + kc * 4));
            a_s[kc*4+0][row] = v.x; a_s[kc*4+1][row] = v.y;
            a_s[kc*4+2][row] = v.z; a_s[kc*4+3][row] = v.w;
        }
        if (TB) {
#pragma unroll
            for (int i = 0; i < 2; i++) {
                int f4 = tid + 256 * i;
                int col = f4 >> 2, kc = f4 & 3;
                float4 v = *(const float4*)(W + (size_t)(n0 + col) * K + (k0 + kc * 4));
                b_s[kc*4+0][col] = v.x; b_s[kc*4+1][col] = v.y;
                b_s[kc*4+2][col] = v.z; b_s[kc*4+3][col] = v.w;
            }
        } else {
#pragma unroll
            for (int i = 0; i < 2; i++) {
                int f4 = tid + 256 * i;
                int kk = f4 >> 5, c4 = f4 & 31;
                float4 v = *(const float4*)(W + (size_t)(k0 + kk) * N + (n0 + c4 * 4));
                b_s[kk][c4*4+0] = v.x; b_s[kk][c4*4+1] = v.y;
                b_s[kk][c4*4+2] = v.z; b_s[kk][c4*4+3] = v.w;
            }
        }
        __syncthreads();
#pragma unroll
        for (int kk = 0; kk < 16; kk++) {
            float4 af0 = *(const float4*)&a_s[kk][ty * 8];
            float4 af1 = *(const float4*)&a_s[kk][ty * 8 + 4];
            float4 bf0 = *(const float4*)&b_s[kk][tx * 8];
            float4 bf1 = *(const float4*)&b_s[kk][tx * 8 + 4];
            float af[8] = {af0.x, af0.y, af0.z, af0.w, af1.x, af1.y, af1.z, af1.w};
            float bf[8] = {bf0.x, bf0.y, bf0.z, bf0.w, bf1.x, bf1.y, bf1.z, bf1.w};
#pragma unroll
            for (int i = 0; i < 8; i++)
#pragma unroll
                for (int j = 0; j < 8; j++)
                    acc[i][j] = fmaf(af[i], bf[j], acc[i][j]);
        }
        __syncthreads();
    }
#pragma unroll
    for (int i = 0; i < 8; i++) {
        int row = m0 + ty * 8 + i;
#pragma unroll
        for (int j = 0; j < 8; j++) {
            int col = n0 + tx * 8 + j;
            float v = acc[i][j] + bias[col];
            size_t oidx;
            if (PERM) {
                int bb = row >> 11; int tt = row & 2047;
                oidx = ((size_t)tt * 8 + bb) * (size_t)N + col;
            } else {
                oidx = (size_t)row * N + col;
            }
            if (OUTBF16) ((unsigned short*)out)[oidx] = f2bf(v);
            else         ((float*)out)[oidx] = v;
        }
    }
}

// ---------------------------------------------------------------------------
// Persistent BiLSTM recurrence.
// Grid: 128 blocks = 2 directions x 64 slice-groups; 256 threads each.
// WG (d,g) owns h-slice j in [g*8, g*8+8) -> 32 rows of Whh (all 4 gates).
// Weights live in registers; h exchanged via global hbuf + sense barrier.
// ---------------------------------------------------------------------------
__global__ __launch_bounds__(256)
void lstm_rec_kernel(const unsigned short* __restrict__ pre_f,
                     const unsigned short* __restrict__ pre_b,
                     const float* __restrict__ Whh_f,
                     const float* __restrict__ Whh_b,
                     float* __restrict__ hbuf,   // [2][2][8][512] f32
                     int* __restrict__ syn,      // [2] {count, sense} spaced
                     unsigned short* __restrict__ seq) // [8][2048][1024] bf16
{
    const int tid = threadIdx.x;
    const int d = blockIdx.x >> 6;
    const int g = blockIdx.x & 63;
    const unsigned short* pre = d ? pre_b : pre_f;
    const float* Whh = d ? Whh_b : Whh_f;
    float* hb = hbuf + (size_t)d * 2 * 8 * 512;
    int* cntp = syn + d * 64;
    int* snsp = syn + d * 64 + 16;

    __shared__ float h_s[4096];          // [8][512]
    __shared__ float gate_s[8][33];      // [b][m], m: i0..7 f0..7 g0..7 o0..7

    const int m2 = tid >> 4;             // 0..15 -> rows m2 and m2+16
    const int tk = tid & 15;             // k slice
    float wA[32], wB[32];
    {
        const int mA = m2, mB = m2 + 16;
        const int growA = (mA >> 3) * 512 + g * 8 + (mA & 7);
        const int growB = (mB >> 3) * 512 + g * 8 + (mB & 7);
#pragma unroll
        for (int qq = 0; qq < 8; qq++) {
            float4 va = *(const float4*)(Whh + (size_t)growA * 512 + (qq * 16 + tk) * 4);
            float4 vb = *(const float4*)(Whh + (size_t)growB * 512 + (qq * 16 + tk) * 4);
            wA[qq*4+0] = va.x; wA[qq*4+1] = va.y; wA[qq*4+2] = va.z; wA[qq*4+3] = va.w;
            wB[qq*4+0] = vb.x; wB[qq*4+1] = vb.y; wB[qq*4+2] = vb.z; wB[qq*4+3] = vb.w;
        }
    }
    const int ub = tid >> 3;     // update-phase batch (tid<64)
    const int uj = tid & 7;
    const int ujj = g * 8 + uj;
    float cst = 0.f;
    int local_sense = 0;

    for (int s = 0; s < 2048; s++) {
        const int t = d ? (2047 - s) : s;
        const float* hin = hb + (size_t)(s & 1) * 4096;
        float* hout = hb + (size_t)((s + 1) & 1) * 4096;

        // prefetch this step's pre-activations (update threads only)
        float pv0 = 0.f, pv1 = 0.f, pv2 = 0.f, pv3 = 0.f;
        if (tid < 64) {
            const size_t pb = ((size_t)t * 8 + ub) * 2048;
            pv0 = bf2f(pre[pb + ujj]);
            pv1 = bf2f(pre[pb + 512 + ujj]);
            pv2 = bf2f(pre[pb + 1024 + ujj]);
            pv3 = bf2f(pre[pb + 1536 + ujj]);
        }
        // stage h_{s-1} into LDS
        {
            const float4* src = (const float4*)hin;
            float4* dst = (float4*)h_s;
#pragma unroll
            for (int i = 0; i < 4; i++) dst[tid + 256 * i] = src[tid + 256 * i];
        }
        __syncthreads();

#pragma unroll 1
        for (int b2 = 0; b2 < 8; b2++) {
            const float4* h4 = (const float4*)(h_s + b2 * 512);
            float s0 = 0.f, s1 = 0.f;
#pragma unroll
            for (int qq = 0; qq < 8; qq++) {
                float4 hv = h4[qq * 16 + tk];
                s0 += hv.x * wA[qq*4+0] + hv.y * wA[qq*4+1] + hv.z * wA[qq*4+2] + hv.w * wA[qq*4+3];
                s1 += hv.x * wB[qq*4+0] + hv.y * wB[qq*4+1] + hv.z * wB[qq*4+2] + hv.w * wB[qq*4+3];
            }
#pragma unroll
            for (int off = 1; off < 16; off <<= 1) {
                s0 += __shfl_xor(s0, off);
                s1 += __shfl_xor(s1, off);
            }
            if (tk == 0) { gate_s[b2][m2] = s0; gate_s[b2][m2 + 16] = s1; }
        }
        __syncthreads();

        if (tid < 64) {
            float zi = gate_s[ub][uj]      + pv0;
            float zf = gate_s[ub][8 + uj]  + pv1;
            float zg = gate_s[ub][16 + uj] + pv2;
            float zo = gate_s[ub][24 + uj] + pv3;
            float gi = 1.f / (1.f + __expf(-zi));
            float gf = 1.f / (1.f + __expf(-zf));
            float go = 1.f / (1.f + __expf(-zo));
            cst = gf * cst + gi * tanhf(zg);
            float hv = go * tanhf(cst);
            hout[ub * 512 + ujj] = hv;
            seq[((size_t)ub * 2048 + t) * 1024 + d * 512 + ujj] = f2bf(hv);
            __threadfence();
        }
        __syncthreads();

        // per-direction sense-reversing barrier over 64 WGs
        local_sense ^= 1;
        if (tid == 0) {
            int prev = __hip_atomic_fetch_add(cntp, 1, __ATOMIC_ACQ_REL, __HIP_MEMORY_SCOPE_AGENT);
            if (prev == 63) {
                __hip_atomic_store(cntp, 0, __ATOMIC_RELAXED, __HIP_MEMORY_SCOPE_AGENT);
                __hip_atomic_store(snsp, local_sense, __ATOMIC_RELEASE, __HIP_MEMORY_SCOPE_AGENT);
            } else {
                int it = 0;
                while (__hip_atomic_load(snsp, __ATOMIC_ACQUIRE, __HIP_MEMORY_SCOPE_AGENT) != local_sense) {
                    if (++it > 300000) break;  // safety: never hang forever
                    __builtin_amdgcn_s_sleep(1);
                }
            }
        }
        __syncthreads();
    }
}

// ---------------------------------------------------------------------------
// Span mean pooling + LayerNorm. 256 blocks = (b,n); 256 threads (4 dims each)
// ---------------------------------------------------------------------------
__global__ __launch_bounds__(256)
void pool_ln_kernel(const unsigned short* __restrict__ seq,
                    const int* __restrict__ heads, const int* __restrict__ tails,
                    const float* __restrict__ lng, const float* __restrict__ lnb,
                    float* __restrict__ xln)
{
    const int bn = blockIdx.x;
    const int b = bn >> 5;
    const int tid = threadIdx.x;
    const int head = heads[bn], tail = tails[bn];
    float a0 = 0.f, a1 = 0.f, a2 = 0.f, a3 = 0.f;
    for (int t = head + 1; t < tail; t++) {
        const unsigned short* p = seq + ((size_t)b * 2048 + t) * 1024 + tid * 4;
        uint2 w = *(const uint2*)p;
        a0 += bf2f((unsigned short)(w.x & 0xffff));
        a1 += bf2f((unsigned short)(w.x >> 16));
        a2 += bf2f((unsigned short)(w.y & 0xffff));
        a3 += bf2f((unsigned short)(w.y >> 16));
    }
    float cnt = (float)(tail - head - 1);
    float x0 = a0 / cnt, x1 = a1 / cnt, x2 = a2 / cnt, x3 = a3 / cnt;
    float s1 = x0 + x1 + x2 + x3;
    float s2 = x0*x0 + x1*x1 + x2*x2 + x3*x3;
#pragma unroll
    for (int off = 1; off < 64; off <<= 1) { s1 += __shfl_xor(s1, off); s2 += __shfl_xor(s2, off); }
    __shared__ float red[8];
    if ((tid & 63) == 0) { int w = tid >> 6; red[w] = s1; red[4 + w] = s2; }
    __syncthreads();
    s1 = red[0] + red[1] + red[2] + red[3];
    s2 = red[4] + red[5] + red[6] + red[7];
    float m = s1 * (1.f / 1024.f);
    float var = s2 * (1.f / 1024.f) - m * m;
    float inv = rsqrtf(var + 1e-5f);
    int c = tid * 4;
    float* o = xln + (size_t)bn * 1024 + c;
    o[0] = (x0 - m) * inv * lng[c+0] + lnb[c+0];
    o[1] = (x1 - m) * inv * lng[c+1] + lnb[c+1];
    o[2] = (x2 - m) * inv * lng[c+2] + lnb[c+2];
    o[3] = (x3 - m) * inv * lng[c+3] + lnb[c+3];
}

// ---------------------------------------------------------------------------
// Relative-key attention over spans. 128 blocks = (b,h); 256 threads.
// ---------------------------------------------------------------------------
__global__ __launch_bounds__(256)
void attn_kernel(const float* __restrict__ q, const float* __restrict__ k,
                 const float* __restrict__ v, const float* __restrict__ dist_emb,
                 const float* __restrict__ mask, float* __restrict__ ctx)
{
    __shared__ float q_s[32][65], k_s[32][65], v_s[32][65];
    __shared__ float pe_s[63][65];
    __shared__ float p_s[32][33];
    __shared__ float mk[32];
    const int tid = threadIdx.x;
    const int b = blockIdx.x >> 4, h = blockIdx.x & 15;

    for (int i = tid; i < 32 * 16; i += 256) {
        int n = i >> 4, c = (i & 15) * 4;
        const size_t base = ((size_t)(b * 32 + n)) * 1024 + h * 64 + c;
        float4 qv = *(const float4*)(q + base);
        float4 kv = *(const float4*)(k + base);
        float4 vv = *(const float4*)(v + base);
        q_s[n][c] = qv.x; q_s[n][c+1] = qv.y; q_s[n][c+2] = qv.z; q_s[n][c+3] = qv.w;
        k_s[n][c] = kv.x; k_s[n][c+1] = kv.y; k_s[n][c+2] = kv.z; k_s[n][c+3] = kv.w;
        v_s[n][c] = vv.x; v_s[n][c+1] = vv.y; v_s[n][c+2] = vv.z; v_s[n][c+3] = vv.w;
    }
    for (int i = tid; i < 63 * 16; i += 256) {
        int x = i >> 4, c = (i & 15) * 4;
        float4 pv = *(const float4*)(dist_emb + (size_t)(480 + x) * 64 + c);
        pe_s[x][c] = pv.x; pe_s[x][c+1] = pv.y; pe_s[x][c+2] = pv.z; pe_s[x][c+3] = pv.w;
    }
    if (tid < 32) mk[tid] = mask[b * 32 + tid];
    __syncthreads();

#pragma unroll
    for (int pi = 0; pi < 4; pi++) {
        int p = tid + 256 * pi;
        int l = p >> 5, r = p & 31;
        const float* qr = q_s[l];
        const float* kr = k_s[r];
        const float* pr = pe_s[l - r + 31];
        float acc = 0.f;
#pragma unroll
        for (int dd = 0; dd < 64; dd++) acc = fmaf(qr[dd], kr[dd] + pr[dd], acc);
        p_s[l][r] = acc * 0.125f + (1.f - mk[r]) * (-10000.f);
    }
    __syncthreads();
    {
        int l = tid >> 3, c = tid & 7;
        float v0 = p_s[l][c], v1 = p_s[l][c+8], v2 = p_s[l][c+16], v3 = p_s[l][c+24];
        float mx = fmaxf(fmaxf(v0, v1), fmaxf(v2, v3));
#pragma unroll
        for (int off = 1; off < 8; off <<= 1) mx = fmaxf(mx, __shfl_xor(mx, off));
        float e0 = __expf(v0 - mx), e1 = __expf(v1 - mx), e2 = __expf(v2 - mx), e3 = __expf(v3 - mx);
        float sm = e0 + e1 + e2 + e3;
#pragma unroll
        for (int off = 1; off < 8; off <<= 1) sm += __shfl_xor(sm, off);
        float inv = 1.f / sm;
        p_s[l][c] = e0 * inv; p_s[l][c+8] = e1 * inv; p_s[l][c+16] = e2 * inv; p_s[l][c+24] = e3 * inv;
    }
    __syncthreads();
    {
        int l = tid >> 3, dg = tid & 7;
        float o[8] = {0, 0, 0, 0, 0, 0, 0, 0};
#pragma unroll 4
        for (int r = 0; r < 32; r++) {
            float pv = p_s[l][r];
#pragma unroll
            for (int j = 0; j < 8; j++) o[j] = fmaf(pv, v_s[r][dg * 8 + j], o[j]);
        }
        size_t base = ((size_t)(b * 32 + l)) * 1024 + h * 64 + dg * 8;
#pragma unroll
        for (int j = 0; j < 8; j++) ctx[base + j] = o[j];
    }
}

// ---------------------------------------------------------------------------
// Residual + LayerNorm (BertSelfOutput): out = LN(tmp + xln)
// ---------------------------------------------------------------------------
__global__ __launch_bounds__(256)
void resid_ln_kernel(const float* __restrict__ tmp, const float* __restrict__ xln,
                     const float* __restrict__ g, const float* __restrict__ be,
                     float* __restrict__ out)
{
    const int bn = blockIdx.x;
    const int tid = threadIdx.x;
    size_t base = (size_t)bn * 1024 + tid * 4;
    float4 a = *(const float4*)(tmp + base);
    float4 r = *(const float4*)(xln + base);
    float x0 = a.x + r.x, x1 = a.y + r.y, x2 = a.z + r.z, x3 = a.w + r.w;
    float s1 = x0 + x1 + x2 + x3;
    float s2 = x0*x0 + x1*x1 + x2*x2 + x3*x3;
#pragma unroll
    for (int off = 1; off < 64; off <<= 1) { s1 += __shfl_xor(s1, off); s2 += __shfl_xor(s2, off); }
    __shared__ float red[8];
    if ((tid & 63) == 0) { int w = tid >> 6; red[w] = s1; red[4 + w] = s2; }
    __syncthreads();
    s1 = red[0] + red[1] + red[2] + red[3];
    s2 = red[4] + red[5] + red[6] + red[7];
    float m = s1 * (1.f / 1024.f);
    float var = s2 * (1.f / 1024.f) - m * m;
    float inv = rsqrtf(var + 1e-5f);
    int c = tid * 4;
    out[base + 0] = (x0 - m) * inv * g[c+0] + be[c+0];
    out[base + 1] = (x1 - m) * inv * g[c+1] + be[c+1];
    out[base + 2] = (x2 - m) * inv * g[c+2] + be[c+2];
    out[base + 3] = (x3 - m) * inv * g[c+3] + be[c+3];
}

// ---------------------------------------------------------------------------
// Classifier: logits[bn][c] = attn_out[bn] . Wc[:,c] + bc[c]
// ---------------------------------------------------------------------------
__global__ __launch_bounds__(256)
void classify_kernel(const float* __restrict__ x, const float* __restrict__ Wc,
                     const float* __restrict__ bc, float* __restrict__ out)
{
    const int bn = blockIdx.x;
    const int tid = threadIdx.x;
    const float* row = x + (size_t)bn * 1024;
    float a0 = 0.f, a1 = 0.f, a2 = 0.f;
    for (int kk = tid; kk < 1024; kk += 256) {
        float xv = row[kk];
        a0 = fmaf(xv, Wc[kk * 3 + 0], a0);
        a1 = fmaf(xv, Wc[kk * 3 + 1], a1);
        a2 = fmaf(xv, Wc[kk * 3 + 2], a2);
    }
#pragma unroll
    for (int off = 1; off < 64; off <<= 1) {
        a0 += __shfl_xor(a0, off); a1 += __shfl_xor(a1, off); a2 += __shfl_xor(a2, off);
    }
    __shared__ float red[12];
    if ((tid & 63) == 0) { int w = tid >> 6; red[w*3] = a0; red[w*3+1] = a1; red[w*3+2] = a2; }
    __syncthreads();
    if (tid == 0) {
        out[bn * 3 + 0] = red[0] + red[3] + red[6] + red[9]  + bc[0];
        out[bn * 3 + 1] = red[1] + red[4] + red[7] + red[10] + bc[1];
        out[bn * 3 + 2] = red[2] + red[5] + red[8] + red[11] + bc[2];
    }
}

// ---------------------------------------------------------------------------
// Workspace layout (bytes)
// ---------------------------------------------------------------------------
#define OFF_PREF 0ull                    // bf16 [2048][8][2048]  = 64 MiB
#define OFF_PREB 67108864ull             // bf16 same
#define OFF_SEQ  134217728ull            // bf16 [8][2048][1024]  = 32 MiB
#define OFF_XLN  167772160ull            // f32  [256][1024]
#define OFF_Q    168820736ull
#define OFF_K    169869312ull
#define OFF_V    170917888ull
#define OFF_CTX  171966464ull
#define OFF_TMP  173015040ull
#define OFF_ATT  174063616ull
#define OFF_HBUF 175112192ull            // f32 [2][2][8][512] = 64 KiB
#define OFF_SYNC 175177728ull            // int sync area (512 B)

extern "C" void kernel_launch(void* const* d_in, const int* in_sizes, int n_in,
                              void* d_out, int out_size, void* d_ws, size_t ws_size,
                              hipStream_t stream)
{
    const float* enc   = (const float*)d_in[0];
    const int*   heads = (const int*)d_in[1];
    const int*   tails = (const int*)d_in[2];
    const float* amask = (const float*)d_in[3];
    const float* Wih_f = (const float*)d_in[4];
    const float* Whh_f = (const float*)d_in[5];
    const float* b_f   = (const float*)d_in[6];
    const float* Wih_b = (const float*)d_in[7];
    const float* Whh_b = (const float*)d_in[8];
    const float* b_b   = (const float*)d_in[9];
    const float* ln_g  = (const float*)d_in[10];
    const float* ln_b  = (const float*)d_in[11];
    const float* Wq    = (const float*)d_in[12];
    const float* bq    = (const float*)d_in[13];
    const float* Wk    = (const float*)d_in[14];
    const float* bk    = (const float*)d_in[15];
    const float* Wv    = (const float*)d_in[16];
    const float* bv    = (const float*)d_in[17];
    const float* dist  = (const float*)d_in[18];
    const float* Wo    = (const float*)d_in[19];
    const float* bo    = (const float*)d_in[20];
    const float* ao_g  = (const float*)d_in[21];
    const float* ao_b  = (const float*)d_in[22];
    const float* Wc    = (const float*)d_in[23];
    const float* bc    = (const float*)d_in[24];

    char* ws = (char*)d_ws;
    unsigned short* pre_f = (unsigned short*)(ws + OFF_PREF);
    unsigned short* pre_b = (unsigned short*)(ws + OFF_PREB);
    unsigned short* seqp  = (unsigned short*)(ws + OFF_SEQ);
    float* xlnp = (float*)(ws + OFF_XLN);
    float* qb   = (float*)(ws + OFF_Q);
    float* kb   = (float*)(ws + OFF_K);
    float* vb   = (float*)(ws + OFF_V);
    float* ctxb = (float*)(ws + OFF_CTX);
    float* tmpb = (float*)(ws + OFF_TMP);
    float* attb = (float*)(ws + OFF_ATT);
    float* hbuf = (float*)(ws + OFF_HBUF);
    int*   syn  = (int*)(ws + OFF_SYNC);

    // zero h0/c-state exchange buffer + barrier state (ws is poisoned 0xAA)
    hipMemsetAsync(ws + OFF_HBUF, 0, 65536 + 512, stream);

    // 1) LSTM input projections: pre = enc @ Wih^T + b   (both directions)
    gemm_f32<1, 1, 1><<<dim3(16, 128), 256, 0, stream>>>(enc, Wih_f, b_f, pre_f, 16384, 2048, 1024);
    gemm_f32<1, 1, 1><<<dim3(16, 128), 256, 0, stream>>>(enc, Wih_b, b_b, pre_b, 16384, 2048, 1024);

    // 2) Serial BiLSTM recurrence (persistent, flag-synced)
    lstm_rec_kernel<<<128, 256, 0, stream>>>(pre_f, pre_b, Whh_f, Whh_b, hbuf, syn, seqp);

    // 3) Span mean pooling + LayerNorm
    pool_ln_kernel<<<256, 256, 0, stream>>>(seqp, heads, tails, ln_g, ln_b, xlnp);

    // 4) q,k,v projections
    gemm_f32<0, 0, 0><<<dim3(8, 2), 256, 0, stream>>>(xlnp, Wq, bq, qb, 256, 1024, 1024);
    gemm_f32<0, 0, 0><<<dim3(8, 2), 256, 0, stream>>>(xlnp, Wk, bk, kb, 256, 1024, 1024);
    gemm_f32<0, 0, 0><<<dim3(8, 2), 256, 0, stream>>>(xlnp, Wv, bv, vb, 256, 1024, 1024);

    // 5) relative-key attention
    attn_kernel<<<128, 256, 0, stream>>>(qb, kb, vb, dist, amask, ctxb);

    // 6) output projection + residual LN
    gemm_f32<0, 0, 0><<<dim3(8, 2), 256, 0, stream>>>(ctxb, Wo, bo, tmpb, 256, 1024, 1024);
    resid_ln_kernel<<<256, 256, 0, stream>>>(tmpb, xlnp, ao_g, ao_b, attb);

    // 7) classifier -> d_out [8,32,3] f32
    classify_kernel<<<256, 256, 0, stream>>>(attb, Wc, bc, (float*)d_out);
}

// Round 3
// 14811.757 us; speedup vs baseline: 2.1605x; 2.1605x over previous
//
#include <hip/hip_runtime.h>
#include <hip/hip_bf16.h>

// Problem constants
#define BSZ   8
#define SEQL  2048
#define HID   1024
#define HH    512
#define NSP   32
#define NHEAD 16
#define HDIM  64

__device__ __forceinline__ float bf2f(unsigned short u) {
    unsigned int x = ((unsigned int)u) << 16;
    return __uint_as_float(x);
}
__device__ __forceinline__ unsigned short f2bf(float f) {
    unsigned int x = __float_as_uint(f);
    unsigned int r = (x + 0x7fffu + ((x >> 16) & 1u)) >> 16;
    return (unsigned short)r;
}

// --- cache-bypassing (coherence-point) access helpers -----------------------
__device__ __forceinline__ void ldcg4x4(const float* p0, const float* p1,
                                        const float* p2, const float* p3,
                                        float4& a, float4& b, float4& c, float4& d) {
    asm volatile(
        "global_load_dwordx4 %0, %4, off sc0 sc1\n"
        "global_load_dwordx4 %1, %5, off sc0 sc1\n"
        "global_load_dwordx4 %2, %6, off sc0 sc1\n"
        "global_load_dwordx4 %3, %7, off sc0 sc1\n"
        "s_waitcnt vmcnt(0)"
        : "=&v"(a), "=&v"(b), "=&v"(c), "=&v"(d)
        : "v"(p0), "v"(p1), "v"(p2), "v"(p3)
        : "memory");
}
__device__ __forceinline__ void stcg_wait(float* p, float v) {
    asm volatile("global_store_dword %0, %1, off sc0 sc1\n"
                 "s_waitcnt vmcnt(0)"
                 :: "v"(p), "v"(v) : "memory");
}
__device__ __forceinline__ void stcg_i(int* p, int v) {
    asm volatile("global_store_dword %0, %1, off sc0 sc1"
                 :: "v"(p), "v"(v) : "memory");
}
__device__ __forceinline__ int ldcg_i(const int* p) {
    int v;
    asm volatile("global_load_dword %0, %1, off sc0 sc1\n"
                 "s_waitcnt vmcnt(0)"
                 : "=&v"(v) : "v"(p) : "memory");
    return v;
}

// ---------------------------------------------------------------------------
// Generic tiled f32 GEMM: C[row,col] = sum_k X[row,k] * W(k,col) + bias[col]
// TB=1: W is [N,K] (use W[col][k])   TB=0: W is [K,N]
// PERM=1: output index permuted for LSTM pre layout [t][b][m] (row = b*2048+t)
// OUTBF16=1: store bf16, else f32.
// Tiles 128x128, BK=16, 256 threads, 8x8 per thread.
// ---------------------------------------------------------------------------
template<int TB, int OUTBF16, int PERM>
__global__ __launch_bounds__(256)
void gemm_f32(const float* __restrict__ X, const float* __restrict__ W,
              const float* __restrict__ bias, void* __restrict__ out,
              int M, int N, int K)
{
    __shared__ float a_s[16][132];
    __shared__ float b_s[16][132];
    const int tid = threadIdx.x;
    const int n0 = blockIdx.x * 128;
    const int m0 = blockIdx.y * 128;
    const int tx = tid & 15, ty = tid >> 4;
    float acc[8][8];
#pragma unroll
    for (int i = 0; i < 8; i++)
#pragma unroll
        for (int j = 0; j < 8; j++) acc[i][j] = 0.f;

    for (int k0 = 0; k0 < K; k0 += 16) {
#pragma unroll
        for (int i = 0; i < 2; i++) {
            int f4 = tid + 256 * i;
            int row = f4 >> 2, kc = f4 & 3;
            float4 v = *(const float4*)(X + (size_t)(m0 + row) * K + (k0 + kc * 4));
            a_s[kc*4+0][row] = v.x; a_s[kc*4+1][row] = v.y;
            a_s[kc*4+2][row] = v.z; a_s[kc*4+3][row] = v.w;
        }
        if (TB) {
#pragma unroll
            for (int i = 0; i < 2; i++) {
                int f4 = tid + 256 * i;
                int col = f4 >> 2, kc = f4 & 3;
                float4 v = *(const float4*)(W + (size_t)(n0 + col) * K + (k0 + kc * 4));
                b_s[kc*4+0][col] = v.x; b_s[kc*4+1][col] = v.y;
                b_s[kc*4+2][col] = v.z; b_s[kc*4+3][col] = v.w;
            }
        } else {
#pragma unroll
            for (int i = 0; i < 2; i++) {
                int f4 = tid + 256 * i;
                int kk = f4 >> 5, c4 = f4 & 31;
                float4 v = *(const float4*)(W + (size_t)(k0 + kk) * N + (n0 + c4 * 4));
                b_s[kk][c4*4+0] = v.x; b_s[kk][c4*4+1] = v.y;
                b_s[kk][c4*4+2] = v.z; b_s[kk][c4*4+3] = v.w;
            }
        }
        __syncthreads();
#pragma unroll
        for (int kk = 0; kk < 16; kk++) {
            float4 af0 = *(const float4*)&a_s[kk][ty * 8];
            float4 af1 = *(const float4*)&a_s[kk][ty * 8 + 4];
            float4 bf0 = *(const float4*)&b_s[kk][tx * 8];
            float4 bf1 = *(const float4*)&b_s[kk][tx * 8 + 4];
            float af[8] = {af0.x, af0.y, af0.z, af0.w, af1.x, af1.y, af1.z, af1.w};
            float bf[8] = {bf0.x, bf0.y, bf0.z, bf0.w, bf1.x, bf1.y, bf1.z, bf1.w};
#pragma unroll
            for (int i = 0; i < 8; i++)
#pragma unroll
                for (int j = 0; j < 8; j++)
                    acc[i][j] = fmaf(af[i], bf[j], acc[i][j]);
        }
        __syncthreads();
    }
#pragma unroll
    for (int i = 0; i < 8; i++) {
        int row = m0 + ty * 8 + i;
#pragma unroll
        for (int j = 0; j < 8; j++) {
            int col = n0 + tx * 8 + j;
            float v = acc[i][j] + bias[col];
            size_t oidx;
            if (PERM) {
                int bb = row >> 11; int tt = row & 2047;
                oidx = ((size_t)tt * 8 + bb) * (size_t)N + col;
            } else {
                oidx = (size_t)row * N + col;
            }
            if (OUTBF16) ((unsigned short*)out)[oidx] = f2bf(v);
            else         ((float*)out)[oidx] = v;
        }
    }
}

// ---------------------------------------------------------------------------
// Persistent BiLSTM recurrence.
// Grid: 128 blocks = 2 directions x 64 slice-groups; 256 threads each.
// WG (d,g) owns h-slice j in [g*8, g*8+8) -> 32 rows of Whh (all 4 gates).
// Weights live in registers. h exchange: distributed per-WG step flags +
// sc0/sc1 (coherence-point) loads/stores — no fences, no central atomic.
// ---------------------------------------------------------------------------
__global__ __launch_bounds__(256)
void lstm_rec_kernel(const unsigned short* __restrict__ pre_f,
                     const unsigned short* __restrict__ pre_b,
                     const float* __restrict__ Whh_f,
                     const float* __restrict__ Whh_b,
                     float* __restrict__ hbuf,   // [2][2][8][512] f32
                     int* __restrict__ flags,    // [2][64][32] ints (128B apart)
                     unsigned short* __restrict__ seq) // [8][2048][1024] bf16
{
    const int tid = threadIdx.x;
    const int d = blockIdx.x >> 6;
    const int g = blockIdx.x & 63;
    const unsigned short* pre = d ? pre_b : pre_f;
    const float* Whh = d ? Whh_b : Whh_f;
    float* hb = hbuf + (size_t)d * 2 * 8 * 512;
    int* flg = flags + d * 64 * 32;
    int* myflag = flg + g * 32;

    __shared__ float h_s[4096];          // [8][512]
    __shared__ float gate_s[8][33];      // [b][m], m: i0..7 f0..7 g0..7 o0..7

    const int m2 = tid >> 4;             // 0..15 -> rows m2 and m2+16
    const int tk = tid & 15;             // k slice
    float wA[32], wB[32];
    {
        const int mA = m2, mB = m2 + 16;
        const int growA = (mA >> 3) * 512 + g * 8 + (mA & 7);
        const int growB = (mB >> 3) * 512 + g * 8 + (mB & 7);
#pragma unroll
        for (int qq = 0; qq < 8; qq++) {
            float4 va = *(const float4*)(Whh + (size_t)growA * 512 + (qq * 16 + tk) * 4);
            float4 vb = *(const float4*)(Whh + (size_t)growB * 512 + (qq * 16 + tk) * 4);
            wA[qq*4+0] = va.x; wA[qq*4+1] = va.y; wA[qq*4+2] = va.z; wA[qq*4+3] = va.w;
            wB[qq*4+0] = vb.x; wB[qq*4+1] = vb.y; wB[qq*4+2] = vb.z; wB[qq*4+3] = vb.w;
        }
    }
    const int ub = tid >> 3;     // update-phase batch (tid<64)
    const int uj = tid & 7;
    const int ujj = g * 8 + uj;
    float cst = 0.f;

    for (int s = 0; s < 2048; s++) {
        const int t = d ? (2047 - s) : s;
        const float* hin = hb + (size_t)(s & 1) * 4096;       // h_{s-1}
        float* hout = hb + (size_t)((s + 1) & 1) * 4096;      // h_s

        // prefetch this step's pre-activations (plain cached loads, overlap poll)
        float pv0 = 0.f, pv1 = 0.f, pv2 = 0.f, pv3 = 0.f;
        if (tid < 64) {
            const size_t pb = ((size_t)t * 8 + ub) * 2048;
            pv0 = bf2f(pre[pb + ujj]);
            pv1 = bf2f(pre[pb + 512 + ujj]);
            pv2 = bf2f(pre[pb + 1024 + ujj]);
            pv3 = bf2f(pre[pb + 1536 + ujj]);
        }

        // wait: h_{s-1} published by all 64 WGs (flags >= s). Wave 0, parallel.
        if (tid < 64) {
            const int* fp = flg + tid * 32;
            int guard = 0;
            while (1) {
                int f = ldcg_i(fp);
                if (__all(f >= s)) break;
                if (++guard > (1 << 22)) break;     // hang-safety
                __builtin_amdgcn_s_sleep(1);
            }
        }
        __syncthreads();

        // stage h_{s-1} into LDS (coherence-point reads, 4 in flight)
        {
            const float* base = hin + tid * 4;
            float4 va, vb2, vc, vd2;
            ldcg4x4(base, base + 1024, base + 2048, base + 3072, va, vb2, vc, vd2);
            float4* dst = (float4*)h_s;
            dst[tid] = va; dst[tid + 256] = vb2; dst[tid + 512] = vc; dst[tid + 768] = vd2;
        }
        __syncthreads();

#pragma unroll 1
        for (int b2 = 0; b2 < 8; b2++) {
            const float4* h4 = (const float4*)(h_s + b2 * 512);
            float s0 = 0.f, s1 = 0.f;
#pragma unroll
            for (int qq = 0; qq < 8; qq++) {
                float4 hv = h4[qq * 16 + tk];
                s0 += hv.x * wA[qq*4+0] + hv.y * wA[qq*4+1] + hv.z * wA[qq*4+2] + hv.w * wA[qq*4+3];
                s1 += hv.x * wB[qq*4+0] + hv.y * wB[qq*4+1] + hv.z * wB[qq*4+2] + hv.w * wB[qq*4+3];
            }
#pragma unroll
            for (int off = 1; off < 16; off <<= 1) {
                s0 += __shfl_xor(s0, off);
                s1 += __shfl_xor(s1, off);
            }
            if (tk == 0) { gate_s[b2][m2] = s0; gate_s[b2][m2 + 16] = s1; }
        }
        __syncthreads();

        if (tid < 64) {
            float zi = gate_s[ub][uj]      + pv0;
            float zf = gate_s[ub][8 + uj]  + pv1;
            float zg = gate_s[ub][16 + uj] + pv2;
            float zo = gate_s[ub][24 + uj] + pv3;
            float gi = 1.f / (1.f + __expf(-zi));
            float gf = 1.f / (1.f + __expf(-zf));
            float go = 1.f / (1.f + __expf(-zo));
            cst = gf * cst + gi * tanhf(zg);
            float hv = go * tanhf(cst);
            seq[((size_t)ub * 2048 + t) * 1024 + d * 512 + ujj] = f2bf(hv);  // plain store
            stcg_wait(hout + ub * 512 + ujj, hv);   // coherent store + vmcnt(0)
        }
        __syncthreads();
        // publish: all 64 h-values of this WG are at the coherence point
        if (tid == 0) stcg_i(myflag, s + 1);
    }
}

// ---------------------------------------------------------------------------
// Span mean pooling + LayerNorm. 256 blocks = (b,n); 256 threads (4 dims each)
// ---------------------------------------------------------------------------
__global__ __launch_bounds__(256)
void pool_ln_kernel(const unsigned short* __restrict__ seq,
                    const int* __restrict__ heads, const int* __restrict__ tails,
                    const float* __restrict__ lng, const float* __restrict__ lnb,
                    float* __restrict__ xln)
{
    const int bn = blockIdx.x;
    const int b = bn >> 5;
    const int tid = threadIdx.x;
    const int head = heads[bn], tail = tails[bn];
    float a0 = 0.f, a1 = 0.f, a2 = 0.f, a3 = 0.f;
    for (int t = head + 1; t < tail; t++) {
        const unsigned short* p = seq + ((size_t)b * 2048 + t) * 1024 + tid * 4;
        uint2 w = *(const uint2*)p;
        a0 += bf2f((unsigned short)(w.x & 0xffff));
        a1 += bf2f((unsigned short)(w.x >> 16));
        a2 += bf2f((unsigned short)(w.y & 0xffff));
        a3 += bf2f((unsigned short)(w.y >> 16));
    }
    float cnt = (float)(tail - head - 1);
    float x0 = a0 / cnt, x1 = a1 / cnt, x2 = a2 / cnt, x3 = a3 / cnt;
    float s1 = x0 + x1 + x2 + x3;
    float s2 = x0*x0 + x1*x1 + x2*x2 + x3*x3;
#pragma unroll
    for (int off = 1; off < 64; off <<= 1) { s1 += __shfl_xor(s1, off); s2 += __shfl_xor(s2, off); }
    __shared__ float red[8];
    if ((tid & 63) == 0) { int w = tid >> 6; red[w] = s1; red[4 + w] = s2; }
    __syncthreads();
    s1 = red[0] + red[1] + red[2] + red[3];
    s2 = red[4] + red[5] + red[6] + red[7];
    float m = s1 * (1.f / 1024.f);
    float var = s2 * (1.f / 1024.f) - m * m;
    float inv = rsqrtf(var + 1e-5f);
    int c = tid * 4;
    float* o = xln + (size_t)bn * 1024 + c;
    o[0] = (x0 - m) * inv * lng[c+0] + lnb[c+0];
    o[1] = (x1 - m) * inv * lng[c+1] + lnb[c+1];
    o[2] = (x2 - m) * inv * lng[c+2] + lnb[c+2];
    o[3] = (x3 - m) * inv * lng[c+3] + lnb[c+3];
}

// ---------------------------------------------------------------------------
// Relative-key attention over spans. 128 blocks = (b,h); 256 threads.
// ---------------------------------------------------------------------------
__global__ __launch_bounds__(256)
void attn_kernel(const float* __restrict__ q, const float* __restrict__ k,
                 const float* __restrict__ v, const float* __restrict__ dist_emb,
                 const float* __restrict__ mask, float* __restrict__ ctx)
{
    __shared__ float q_s[32][65], k_s[32][65], v_s[32][65];
    __shared__ float pe_s[63][65];
    __shared__ float p_s[32][33];
    __shared__ float mk[32];
    const int tid = threadIdx.x;
    const int b = blockIdx.x >> 4, h = blockIdx.x & 15;

    for (int i = tid; i < 32 * 16; i += 256) {
        int n = i >> 4, c = (i & 15) * 4;
        const size_t base = ((size_t)(b * 32 + n)) * 1024 + h * 64 + c;
        float4 qv = *(const float4*)(q + base);
        float4 kv = *(const float4*)(k + base);
        float4 vv = *(const float4*)(v + base);
        q_s[n][c] = qv.x; q_s[n][c+1] = qv.y; q_s[n][c+2] = qv.z; q_s[n][c+3] = qv.w;
        k_s[n][c] = kv.x; k_s[n][c+1] = kv.y; k_s[n][c+2] = kv.z; k_s[n][c+3] = kv.w;
        v_s[n][c] = vv.x; v_s[n][c+1] = vv.y; v_s[n][c+2] = vv.z; v_s[n][c+3] = vv.w;
    }
    for (int i = tid; i < 63 * 16; i += 256) {
        int x = i >> 4, c = (i & 15) * 4;
        float4 pv = *(const float4*)(dist_emb + (size_t)(480 + x) * 64 + c);
        pe_s[x][c] = pv.x; pe_s[x][c+1] = pv.y; pe_s[x][c+2] = pv.z; pe_s[x][c+3] = pv.w;
    }
    if (tid < 32) mk[tid] = mask[b * 32 + tid];
    __syncthreads();

#pragma unroll
    for (int pi = 0; pi < 4; pi++) {
        int p = tid + 256 * pi;
        int l = p >> 5, r = p & 31;
        const float* qr = q_s[l];
        const float* kr = k_s[r];
        const float* pr = pe_s[l - r + 31];
        float acc = 0.f;
#pragma unroll
        for (int dd = 0; dd < 64; dd++) acc = fmaf(qr[dd], kr[dd] + pr[dd], acc);
        p_s[l][r] = acc * 0.125f + (1.f - mk[r]) * (-10000.f);
    }
    __syncthreads();
    {
        int l = tid >> 3, c = tid & 7;
        float v0 = p_s[l][c], v1 = p_s[l][c+8], v2 = p_s[l][c+16], v3 = p_s[l][c+24];
        float mx = fmaxf(fmaxf(v0, v1), fmaxf(v2, v3));
#pragma unroll
        for (int off = 1; off < 8; off <<= 1) mx = fmaxf(mx, __shfl_xor(mx, off));
        float e0 = __expf(v0 - mx), e1 = __expf(v1 - mx), e2 = __expf(v2 - mx), e3 = __expf(v3 - mx);
        float sm = e0 + e1 + e2 + e3;
#pragma unroll
        for (int off = 1; off < 8; off <<= 1) sm += __shfl_xor(sm, off);
        float inv = 1.f / sm;
        p_s[l][c] = e0 * inv; p_s[l][c+8] = e1 * inv; p_s[l][c+16] = e2 * inv; p_s[l][c+24] = e3 * inv;
    }
    __syncthreads();
    {
        int l = tid >> 3, dg = tid & 7;
        float o[8] = {0, 0, 0, 0, 0, 0, 0, 0};
#pragma unroll 4
        for (int r = 0; r < 32; r++) {
            float pv = p_s[l][r];
#pragma unroll
            for (int j = 0; j < 8; j++) o[j] = fmaf(pv, v_s[r][dg * 8 + j], o[j]);
        }
        size_t base = ((size_t)(b * 32 + l)) * 1024 + h * 64 + dg * 8;
#pragma unroll
        for (int j = 0; j < 8; j++) ctx[base + j] = o[j];
    }
}

// ---------------------------------------------------------------------------
// Residual + LayerNorm (BertSelfOutput): out = LN(tmp + xln)
// ---------------------------------------------------------------------------
__global__ __launch_bounds__(256)
void resid_ln_kernel(const float* __restrict__ tmp, const float* __restrict__ xln,
                     const float* __restrict__ g, const float* __restrict__ be,
                     float* __restrict__ out)
{
    const int bn = blockIdx.x;
    const int tid = threadIdx.x;
    size_t base = (size_t)bn * 1024 + tid * 4;
    float4 a = *(const float4*)(tmp + base);
    float4 r = *(const float4*)(xln + base);
    float x0 = a.x + r.x, x1 = a.y + r.y, x2 = a.z + r.z, x3 = a.w + r.w;
    float s1 = x0 + x1 + x2 + x3;
    float s2 = x0*x0 + x1*x1 + x2*x2 + x3*x3;
#pragma unroll
    for (int off = 1; off < 64; off <<= 1) { s1 += __shfl_xor(s1, off); s2 += __shfl_xor(s2, off); }
    __shared__ float red[8];
    if ((tid & 63) == 0) { int w = tid >> 6; red[w] = s1; red[4 + w] = s2; }
    __syncthreads();
    s1 = red[0] + red[1] + red[2] + red[3];
    s2 = red[4] + red[5] + red[6] + red[7];
    float m = s1 * (1.f / 1024.f);
    float var = s2 * (1.f / 1024.f) - m * m;
    float inv = rsqrtf(var + 1e-5f);
    int c = tid * 4;
    out[base + 0] = (x0 - m) * inv * g[c+0] + be[c+0];
    out[base + 1] = (x1 - m) * inv * g[c+1] + be[c+1];
    out[base + 2] = (x2 - m) * inv * g[c+2] + be[c+2];
    out[base + 3] = (x3 - m) * inv * g[c+3] + be[c+3];
}

// ---------------------------------------------------------------------------
// Classifier: logits[bn][c] = attn_out[bn] . Wc[:,c] + bc[c]
// ---------------------------------------------------------------------------
__global__ __launch_bounds__(256)
void classify_kernel(const float* __restrict__ x, const float* __restrict__ Wc,
                     const float* __restrict__ bc, float* __restrict__ out)
{
    const int bn = blockIdx.x;
    const int tid = threadIdx.x;
    const float* row = x + (size_t)bn * 1024;
    float a0 = 0.f, a1 = 0.f, a2 = 0.f;
    for (int kk = tid; kk < 1024; kk += 256) {
        float xv = row[kk];
        a0 = fmaf(xv, Wc[kk * 3 + 0], a0);
        a1 = fmaf(xv, Wc[kk * 3 + 1], a1);
        a2 = fmaf(xv, Wc[kk * 3 + 2], a2);
    }
#pragma unroll
    for (int off = 1; off < 64; off <<= 1) {
        a0 += __shfl_xor(a0, off); a1 += __shfl_xor(a1, off); a2 += __shfl_xor(a2, off);
    }
    __shared__ float red[12];
    if ((tid & 63) == 0) { int w = tid >> 6; red[w*3] = a0; red[w*3+1] = a1; red[w*3+2] = a2; }
    __syncthreads();
    if (tid == 0) {
        out[bn * 3 + 0] = red[0] + red[3] + red[6] + red[9]  + bc[0];
        out[bn * 3 + 1] = red[1] + red[4] + red[7] + red[10] + bc[1];
        out[bn * 3 + 2] = red[2] + red[5] + red[8] + red[11] + bc[2];
    }
}

// ---------------------------------------------------------------------------
// Workspace layout (bytes)
// ---------------------------------------------------------------------------
#define OFF_PREF 0ull                    // bf16 [2048][8][2048]  = 64 MiB
#define OFF_PREB 67108864ull             // bf16 same
#define OFF_SEQ  134217728ull            // bf16 [8][2048][1024]  = 32 MiB
#define OFF_XLN  167772160ull            // f32  [256][1024]
#define OFF_Q    168820736ull
#define OFF_K    169869312ull
#define OFF_V    170917888ull
#define OFF_CTX  171966464ull
#define OFF_TMP  173015040ull
#define OFF_ATT  174063616ull
#define OFF_HBUF 175112192ull            // f32 [2][2][8][512] = 64 KiB
#define OFF_SYNC 175177728ull            // int flags [2][64][32] = 16 KiB

extern "C" void kernel_launch(void* const* d_in, const int* in_sizes, int n_in,
                              void* d_out, int out_size, void* d_ws, size_t ws_size,
                              hipStream_t stream)
{
    const float* enc   = (const float*)d_in[0];
    const int*   heads = (const int*)d_in[1];
    const int*   tails = (const int*)d_in[2];
    const float* amask = (const float*)d_in[3];
    const float* Wih_f = (const float*)d_in[4];
    const float* Whh_f = (const float*)d_in[5];
    const float* b_f   = (const float*)d_in[6];
    const float* Wih_b = (const float*)d_in[7];
    const float* Whh_b = (const float*)d_in[8];
    const float* b_b   = (const float*)d_in[9];
    const float* ln_g  = (const float*)d_in[10];
    const float* ln_b  = (const float*)d_in[11];
    const float* Wq    = (const float*)d_in[12];
    const float* bq    = (const float*)d_in[13];
    const float* Wk    = (const float*)d_in[14];
    const float* bk    = (const float*)d_in[15];
    const float* Wv    = (const float*)d_in[16];
    const float* bv    = (const float*)d_in[17];
    const float* dist  = (const float*)d_in[18];
    const float* Wo    = (const float*)d_in[19];
    const float* bo    = (const float*)d_in[20];
    const float* ao_g  = (const float*)d_in[21];
    const float* ao_b  = (const float*)d_in[22];
    const float* Wc    = (const float*)d_in[23];
    const float* bc    = (const float*)d_in[24];

    char* ws = (char*)d_ws;
    unsigned short* pre_f = (unsigned short*)(ws + OFF_PREF);
    unsigned short* pre_b = (unsigned short*)(ws + OFF_PREB);
    unsigned short* seqp  = (unsigned short*)(ws + OFF_SEQ);
    float* xlnp = (float*)(ws + OFF_XLN);
    float* qb   = (float*)(ws + OFF_Q);
    float* kb   = (float*)(ws + OFF_K);
    float* vb   = (float*)(ws + OFF_V);
    float* ctxb = (float*)(ws + OFF_CTX);
    float* tmpb = (float*)(ws + OFF_TMP);
    float* attb = (float*)(ws + OFF_ATT);
    float* hbuf = (float*)(ws + OFF_HBUF);
    int*   flags = (int*)(ws + OFF_SYNC);

    // zero h0 exchange buffer + step flags (ws is poisoned 0xAA)
    hipMemsetAsync(ws + OFF_HBUF, 0, 65536 + 16384, stream);

    // 1) LSTM input projections: pre = enc @ Wih^T + b   (both directions)
    gemm_f32<1, 1, 1><<<dim3(16, 128), 256, 0, stream>>>(enc, Wih_f, b_f, pre_f, 16384, 2048, 1024);
    gemm_f32<1, 1, 1><<<dim3(16, 128), 256, 0, stream>>>(enc, Wih_b, b_b, pre_b, 16384, 2048, 1024);

    // 2) Serial BiLSTM recurrence (persistent, flag-synced)
    lstm_rec_kernel<<<128, 256, 0, stream>>>(pre_f, pre_b, Whh_f, Whh_b, hbuf, flags, seqp);

    // 3) Span mean pooling + LayerNorm
    pool_ln_kernel<<<256, 256, 0, stream>>>(seqp, heads, tails, ln_g, ln_b, xlnp);

    // 4) q,k,v projections
    gemm_f32<0, 0, 0><<<dim3(8, 2), 256, 0, stream>>>(xlnp, Wq, bq, qb, 256, 1024, 1024);
    gemm_f32<0, 0, 0><<<dim3(8, 2), 256, 0, stream>>>(xlnp, Wk, bk, kb, 256, 1024, 1024);
    gemm_f32<0, 0, 0><<<dim3(8, 2), 256, 0, stream>>>(xlnp, Wv, bv, vb, 256, 1024, 1024);

    // 5) relative-key attention
    attn_kernel<<<128, 256, 0, stream>>>(qb, kb, vb, dist, amask, ctxb);

    // 6) output projection + residual LN
    gemm_f32<0, 0, 0><<<dim3(8, 2), 256, 0, stream>>>(ctxb, Wo, bo, tmpb, 256, 1024, 1024);
    resid_ln_kernel<<<256, 256, 0, stream>>>(tmpb, xlnp, ao_g, ao_b, attb);

    // 7) classifier -> d_out [8,32,3] f32
    classify_kernel<<<256, 256, 0, stream>>>(attb, Wc, bc, (float*)d_out);
}

// Round 4
// 14243.449 us; speedup vs baseline: 2.2467x; 1.0399x over previous
//
#include <hip/hip_runtime.h>
#include <hip/hip_bf16.h>

// Problem constants
#define BSZ   8
#define SEQL  2048
#define HID   1024
#define HH    512
#define NSP   32
#define NHEAD 16
#define HDIM  64
#define NREP  4      // h-exchange replication factor (coherence-point fan-out)

__device__ __forceinline__ float bf2f(unsigned short u) {
    unsigned int x = ((unsigned int)u) << 16;
    return __uint_as_float(x);
}
__device__ __forceinline__ unsigned short f2bf(float f) {
    unsigned int x = __float_as_uint(f);
    unsigned int r = (x + 0x7fffu + ((x >> 16) & 1u)) >> 16;
    return (unsigned short)r;
}

// --- cache-bypassing (coherence-point) access helpers -----------------------
__device__ __forceinline__ void ldcg4x4(const float* p0, const float* p1,
                                        const float* p2, const float* p3,
                                        float4& a, float4& b, float4& c, float4& d) {
    asm volatile(
        "global_load_dwordx4 %0, %4, off sc0 sc1\n"
        "global_load_dwordx4 %1, %5, off sc0 sc1\n"
        "global_load_dwordx4 %2, %6, off sc0 sc1\n"
        "global_load_dwordx4 %3, %7, off sc0 sc1\n"
        "s_waitcnt vmcnt(0)"
        : "=&v"(a), "=&v"(b), "=&v"(c), "=&v"(d)
        : "v"(p0), "v"(p1), "v"(p2), "v"(p3)
        : "memory");
}
// store v to 4 replica addresses, then drain to coherence point
__device__ __forceinline__ void stcg4_wait(float* p0, float* p1, float* p2,
                                           float* p3, float v) {
    asm volatile(
        "global_store_dword %0, %4, off sc0 sc1\n"
        "global_store_dword %1, %4, off sc0 sc1\n"
        "global_store_dword %2, %4, off sc0 sc1\n"
        "global_store_dword %3, %4, off sc0 sc1\n"
        "s_waitcnt vmcnt(0)"
        :: "v"(p0), "v"(p1), "v"(p2), "v"(p3), "v"(v) : "memory");
}
__device__ __forceinline__ void stcg_i(int* p, int v) {
    asm volatile("global_store_dword %0, %1, off sc0 sc1"
                 :: "v"(p), "v"(v) : "memory");
}
__device__ __forceinline__ int ldcg_i(const int* p) {
    int v;
    asm volatile("global_load_dword %0, %1, off sc0 sc1\n"
                 "s_waitcnt vmcnt(0)"
                 : "=&v"(v) : "v"(p) : "memory");
    return v;
}

// ---------------------------------------------------------------------------
// Generic tiled f32 GEMM: C[row,col] = sum_k X[row,k] * W(k,col) + bias[col]
// TB=1: W is [N,K] (use W[col][k])   TB=0: W is [K,N]
// PERM=1: output index permuted for LSTM pre layout [t][b][m] (row = b*2048+t)
// OUTBF16=1: store bf16, else f32.
// Tiles 128x128, BK=16, 256 threads, 8x8 per thread.
// ---------------------------------------------------------------------------
template<int TB, int OUTBF16, int PERM>
__global__ __launch_bounds__(256)
void gemm_f32(const float* __restrict__ X, const float* __restrict__ W,
              const float* __restrict__ bias, void* __restrict__ out,
              int M, int N, int K)
{
    __shared__ float a_s[16][132];
    __shared__ float b_s[16][132];
    const int tid = threadIdx.x;
    const int n0 = blockIdx.x * 128;
    const int m0 = blockIdx.y * 128;
    const int tx = tid & 15, ty = tid >> 4;
    float acc[8][8];
#pragma unroll
    for (int i = 0; i < 8; i++)
#pragma unroll
        for (int j = 0; j < 8; j++) acc[i][j] = 0.f;

    for (int k0 = 0; k0 < K; k0 += 16) {
#pragma unroll
        for (int i = 0; i < 2; i++) {
            int f4 = tid + 256 * i;
            int row = f4 >> 2, kc = f4 & 3;
            float4 v = *(const float4*)(X + (size_t)(m0 + row) * K + (k0 + kc * 4));
            a_s[kc*4+0][row] = v.x; a_s[kc*4+1][row] = v.y;
            a_s[kc*4+2][row] = v.z; a_s[kc*4+3][row] = v.w;
        }
        if (TB) {
#pragma unroll
            for (int i = 0; i < 2; i++) {
                int f4 = tid + 256 * i;
                int col = f4 >> 2, kc = f4 & 3;
                float4 v = *(const float4*)(W + (size_t)(n0 + col) * K + (k0 + kc * 4));
                b_s[kc*4+0][col] = v.x; b_s[kc*4+1][col] = v.y;
                b_s[kc*4+2][col] = v.z; b_s[kc*4+3][col] = v.w;
            }
        } else {
#pragma unroll
            for (int i = 0; i < 2; i++) {
                int f4 = tid + 256 * i;
                int kk = f4 >> 5, c4 = f4 & 31;
                float4 v = *(const float4*)(W + (size_t)(k0 + kk) * N + (n0 + c4 * 4));
                b_s[kk][c4*4+0] = v.x; b_s[kk][c4*4+1] = v.y;
                b_s[kk][c4*4+2] = v.z; b_s[kk][c4*4+3] = v.w;
            }
        }
        __syncthreads();
#pragma unroll
        for (int kk = 0; kk < 16; kk++) {
            float4 af0 = *(const float4*)&a_s[kk][ty * 8];
            float4 af1 = *(const float4*)&a_s[kk][ty * 8 + 4];
            float4 bf0 = *(const float4*)&b_s[kk][tx * 8];
            float4 bf1 = *(const float4*)&b_s[kk][tx * 8 + 4];
            float af[8] = {af0.x, af0.y, af0.z, af0.w, af1.x, af1.y, af1.z, af1.w};
            float bf[8] = {bf0.x, bf0.y, bf0.z, bf0.w, bf1.x, bf1.y, bf1.z, bf1.w};
#pragma unroll
            for (int i = 0; i < 8; i++)
#pragma unroll
                for (int j = 0; j < 8; j++)
                    acc[i][j] = fmaf(af[i], bf[j], acc[i][j]);
        }
        __syncthreads();
    }
#pragma unroll
    for (int i = 0; i < 8; i++) {
        int row = m0 + ty * 8 + i;
#pragma unroll
        for (int j = 0; j < 8; j++) {
            int col = n0 + tx * 8 + j;
            float v = acc[i][j] + bias[col];
            size_t oidx;
            if (PERM) {
                int bb = row >> 11; int tt = row & 2047;
                oidx = ((size_t)tt * 8 + bb) * (size_t)N + col;
            } else {
                oidx = (size_t)row * N + col;
            }
            if (OUTBF16) ((unsigned short*)out)[oidx] = f2bf(v);
            else         ((float*)out)[oidx] = v;
        }
    }
}

// ---------------------------------------------------------------------------
// Persistent BiLSTM recurrence.
// Grid: 128 blocks = 2 directions x 64 slice-groups; 256 threads each.
// WG (d,g) owns h-slice j in [g*8, g*8+8) -> 32 rows of Whh (all 4 gates).
// Weights live in registers. h exchange: NREP-replicated buffers + flag
// banks (spread coherence-point fan-in); sc0/sc1 loads/stores, no fences.
// hbuf layout: [2 dir][2 parity][NREP][8*512] f32
// flag layout: [2 dir][NREP][64 wg][32 ints]
// ---------------------------------------------------------------------------
__global__ __launch_bounds__(256)
void lstm_rec_kernel(const unsigned short* __restrict__ pre_f,
                     const unsigned short* __restrict__ pre_b,
                     const float* __restrict__ Whh_f,
                     const float* __restrict__ Whh_b,
                     float* __restrict__ hbuf,
                     int* __restrict__ flags,
                     unsigned short* __restrict__ seq) // [8][2048][1024] bf16
{
    const int tid = threadIdx.x;
    const int d = blockIdx.x >> 6;
    const int g = blockIdx.x & 63;
    const unsigned short* pre = d ? pre_b : pre_f;
    const float* Whh = d ? Whh_b : Whh_f;
    float* hb = hbuf + (size_t)d * 2 * NREP * 4096;
    int* flg = flags + d * NREP * 64 * 32;
    const int rsel = g & (NREP - 1);

    __shared__ float h_s[4096];          // [8][512]
    __shared__ float gate_s[8][33];      // [b][m], m: i0..7 f0..7 g0..7 o0..7

    const int m2 = tid >> 4;             // 0..15 -> rows m2 and m2+16
    const int tk = tid & 15;             // k slice
    float wA[32], wB[32];
    {
        const int mA = m2, mB = m2 + 16;
        const int growA = (mA >> 3) * 512 + g * 8 + (mA & 7);
        const int growB = (mB >> 3) * 512 + g * 8 + (mB & 7);
#pragma unroll
        for (int qq = 0; qq < 8; qq++) {
            float4 va = *(const float4*)(Whh + (size_t)growA * 512 + (qq * 16 + tk) * 4);
            float4 vb = *(const float4*)(Whh + (size_t)growB * 512 + (qq * 16 + tk) * 4);
            wA[qq*4+0] = va.x; wA[qq*4+1] = va.y; wA[qq*4+2] = va.z; wA[qq*4+3] = va.w;
            wB[qq*4+0] = vb.x; wB[qq*4+1] = vb.y; wB[qq*4+2] = vb.z; wB[qq*4+3] = vb.w;
        }
    }
    const int ub = tid >> 3;     // update-phase batch (tid<64)
    const int uj = tid & 7;
    const int ujj = g * 8 + uj;
    float cst = 0.f;

    for (int s = 0; s < 2048; s++) {
        const int t = d ? (2047 - s) : s;
        // replica base for this step's input / next step's output
        const float* hin = hb + (size_t)(s & 1) * (NREP * 4096) + (size_t)rsel * 4096;
        float* hout = hb + (size_t)((s + 1) & 1) * (NREP * 4096);

        // prefetch this step's pre-activations (plain cached loads, overlap poll)
        float pv0 = 0.f, pv1 = 0.f, pv2 = 0.f, pv3 = 0.f;
        if (tid < 64) {
            const size_t pb = ((size_t)t * 8 + ub) * 2048;
            pv0 = bf2f(pre[pb + ujj]);
            pv1 = bf2f(pre[pb + 512 + ujj]);
            pv2 = bf2f(pre[pb + 1024 + ujj]);
            pv3 = bf2f(pre[pb + 1536 + ujj]);
        }

        // wait: h_{s-1} published by all 64 WGs (bank rsel flags >= s). Wave 0.
        if (tid < 64) {
            const int* fp = flg + rsel * (64 * 32) + tid * 32;
            int guard = 0;
            while (1) {
                int f = ldcg_i(fp);
                if (__all(f >= s)) break;
                if (++guard > (1 << 22)) break;     // hang-safety
                __builtin_amdgcn_s_sleep(1);
            }
        }
        __syncthreads();

        // stage h_{s-1} into LDS (coherence-point reads, 4 in flight)
        {
            const float* base = hin + tid * 4;
            float4 va, vb2, vc, vd2;
            ldcg4x4(base, base + 1024, base + 2048, base + 3072, va, vb2, vc, vd2);
            float4* dst = (float4*)h_s;
            dst[tid] = va; dst[tid + 256] = vb2; dst[tid + 512] = vc; dst[tid + 768] = vd2;
        }
        __syncthreads();

#pragma unroll 1
        for (int b2 = 0; b2 < 8; b2++) {
            const float4* h4 = (const float4*)(h_s + b2 * 512);
            float s0 = 0.f, s1 = 0.f;
#pragma unroll
            for (int qq = 0; qq < 8; qq++) {
                float4 hv = h4[qq * 16 + tk];
                s0 += hv.x * wA[qq*4+0] + hv.y * wA[qq*4+1] + hv.z * wA[qq*4+2] + hv.w * wA[qq*4+3];
                s1 += hv.x * wB[qq*4+0] + hv.y * wB[qq*4+1] + hv.z * wB[qq*4+2] + hv.w * wB[qq*4+3];
            }
#pragma unroll
            for (int off = 1; off < 16; off <<= 1) {
                s0 += __shfl_xor(s0, off);
                s1 += __shfl_xor(s1, off);
            }
            if (tk == 0) { gate_s[b2][m2] = s0; gate_s[b2][m2 + 16] = s1; }
        }
        __syncthreads();

        if (tid < 64) {
            float zi = gate_s[ub][uj]      + pv0;
            float zf = gate_s[ub][8 + uj]  + pv1;
            float zg = gate_s[ub][16 + uj] + pv2;
            float zo = gate_s[ub][24 + uj] + pv3;
            float gi = 1.f / (1.f + __expf(-zi));
            float gf = 1.f / (1.f + __expf(-zf));
            float go = 1.f / (1.f + __expf(-zo));
            cst = gf * cst + gi * tanhf(zg);
            float hv = go * tanhf(cst);
            seq[((size_t)ub * 2048 + t) * 1024 + d * 512 + ujj] = f2bf(hv);  // plain store
            float* hp = hout + ub * 512 + ujj;
            stcg4_wait(hp, hp + 4096, hp + 2 * 4096, hp + 3 * 4096, hv);  // 4 replicas + drain
        }
        __syncthreads();
        // publish: all h-values of this WG are at the coherence point; flag all banks
        if (tid == 0) {
#pragma unroll
            for (int r = 0; r < NREP; r++)
                stcg_i(flg + r * (64 * 32) + g * 32, s + 1);
        }
    }
}

// ---------------------------------------------------------------------------
// Span mean pooling + LayerNorm. 256 blocks = (b,n); 256 threads (4 dims each)
// ---------------------------------------------------------------------------
__global__ __launch_bounds__(256)
void pool_ln_kernel(const unsigned short* __restrict__ seq,
                    const int* __restrict__ heads, const int* __restrict__ tails,
                    const float* __restrict__ lng, const float* __restrict__ lnb,
                    float* __restrict__ xln)
{
    const int bn = blockIdx.x;
    const int b = bn >> 5;
    const int tid = threadIdx.x;
    const int head = heads[bn], tail = tails[bn];
    float a0 = 0.f, a1 = 0.f, a2 = 0.f, a3 = 0.f;
    for (int t = head + 1; t < tail; t++) {
        const unsigned short* p = seq + ((size_t)b * 2048 + t) * 1024 + tid * 4;
        uint2 w = *(const uint2*)p;
        a0 += bf2f((unsigned short)(w.x & 0xffff));
        a1 += bf2f((unsigned short)(w.x >> 16));
        a2 += bf2f((unsigned short)(w.y & 0xffff));
        a3 += bf2f((unsigned short)(w.y >> 16));
    }
    float cnt = (float)(tail - head - 1);
    float x0 = a0 / cnt, x1 = a1 / cnt, x2 = a2 / cnt, x3 = a3 / cnt;
    float s1 = x0 + x1 + x2 + x3;
    float s2 = x0*x0 + x1*x1 + x2*x2 + x3*x3;
#pragma unroll
    for (int off = 1; off < 64; off <<= 1) { s1 += __shfl_xor(s1, off); s2 += __shfl_xor(s2, off); }
    __shared__ float red[8];
    if ((tid & 63) == 0) { int w = tid >> 6; red[w] = s1; red[4 + w] = s2; }
    __syncthreads();
    s1 = red[0] + red[1] + red[2] + red[3];
    s2 = red[4] + red[5] + red[6] + red[7];
    float m = s1 * (1.f / 1024.f);
    float var = s2 * (1.f / 1024.f) - m * m;
    float inv = rsqrtf(var + 1e-5f);
    int c = tid * 4;
    float* o = xln + (size_t)bn * 1024 + c;
    o[0] = (x0 - m) * inv * lng[c+0] + lnb[c+0];
    o[1] = (x1 - m) * inv * lng[c+1] + lnb[c+1];
    o[2] = (x2 - m) * inv * lng[c+2] + lnb[c+2];
    o[3] = (x3 - m) * inv * lng[c+3] + lnb[c+3];
}

// ---------------------------------------------------------------------------
// Relative-key attention over spans. 128 blocks = (b,h); 256 threads.
// ---------------------------------------------------------------------------
__global__ __launch_bounds__(256)
void attn_kernel(const float* __restrict__ q, const float* __restrict__ k,
                 const float* __restrict__ v, const float* __restrict__ dist_emb,
                 const float* __restrict__ mask, float* __restrict__ ctx)
{
    __shared__ float q_s[32][65], k_s[32][65], v_s[32][65];
    __shared__ float pe_s[63][65];
    __shared__ float p_s[32][33];
    __shared__ float mk[32];
    const int tid = threadIdx.x;
    const int b = blockIdx.x >> 4, h = blockIdx.x & 15;

    for (int i = tid; i < 32 * 16; i += 256) {
        int n = i >> 4, c = (i & 15) * 4;
        const size_t base = ((size_t)(b * 32 + n)) * 1024 + h * 64 + c;
        float4 qv = *(const float4*)(q + base);
        float4 kv = *(const float4*)(k + base);
        float4 vv = *(const float4*)(v + base);
        q_s[n][c] = qv.x; q_s[n][c+1] = qv.y; q_s[n][c+2] = qv.z; q_s[n][c+3] = qv.w;
        k_s[n][c] = kv.x; k_s[n][c+1] = kv.y; k_s[n][c+2] = kv.z; k_s[n][c+3] = kv.w;
        v_s[n][c] = vv.x; v_s[n][c+1] = vv.y; v_s[n][c+2] = vv.z; v_s[n][c+3] = vv.w;
    }
    for (int i = tid; i < 63 * 16; i += 256) {
        int x = i >> 4, c = (i & 15) * 4;
        float4 pv = *(const float4*)(dist_emb + (size_t)(480 + x) * 64 + c);
        pe_s[x][c] = pv.x; pe_s[x][c+1] = pv.y; pe_s[x][c+2] = pv.z; pe_s[x][c+3] = pv.w;
    }
    if (tid < 32) mk[tid] = mask[b * 32 + tid];
    __syncthreads();

#pragma unroll
    for (int pi = 0; pi < 4; pi++) {
        int p = tid + 256 * pi;
        int l = p >> 5, r = p & 31;
        const float* qr = q_s[l];
        const float* kr = k_s[r];
        const float* pr = pe_s[l - r + 31];
        float acc = 0.f;
#pragma unroll
        for (int dd = 0; dd < 64; dd++) acc = fmaf(qr[dd], kr[dd] + pr[dd], acc);
        p_s[l][r] = acc * 0.125f + (1.f - mk[r]) * (-10000.f);
    }
    __syncthreads();
    {
        int l = tid >> 3, c = tid & 7;
        float v0 = p_s[l][c], v1 = p_s[l][c+8], v2 = p_s[l][c+16], v3 = p_s[l][c+24];
        float mx = fmaxf(fmaxf(v0, v1), fmaxf(v2, v3));
#pragma unroll
        for (int off = 1; off < 8; off <<= 1) mx = fmaxf(mx, __shfl_xor(mx, off));
        float e0 = __expf(v0 - mx), e1 = __expf(v1 - mx), e2 = __expf(v2 - mx), e3 = __expf(v3 - mx);
        float sm = e0 + e1 + e2 + e3;
#pragma unroll
        for (int off = 1; off < 8; off <<= 1) sm += __shfl_xor(sm, off);
        float inv = 1.f / sm;
        p_s[l][c] = e0 * inv; p_s[l][c+8] = e1 * inv; p_s[l][c+16] = e2 * inv; p_s[l][c+24] = e3 * inv;
    }
    __syncthreads();
    {
        int l = tid >> 3, dg = tid & 7;
        float o[8] = {0, 0, 0, 0, 0, 0, 0, 0};
#pragma unroll 4
        for (int r = 0; r < 32; r++) {
            float pv = p_s[l][r];
#pragma unroll
            for (int j = 0; j < 8; j++) o[j] = fmaf(pv, v_s[r][dg * 8 + j], o[j]);
        }
        size_t base = ((size_t)(b * 32 + l)) * 1024 + h * 64 + dg * 8;
#pragma unroll
        for (int j = 0; j < 8; j++) ctx[base + j] = o[j];
    }
}

// ---------------------------------------------------------------------------
// Residual + LayerNorm (BertSelfOutput): out = LN(tmp + xln)
// ---------------------------------------------------------------------------
__global__ __launch_bounds__(256)
void resid_ln_kernel(const float* __restrict__ tmp, const float* __restrict__ xln,
                     const float* __restrict__ g, const float* __restrict__ be,
                     float* __restrict__ out)
{
    const int bn = blockIdx.x;
    const int tid = threadIdx.x;
    size_t base = (size_t)bn * 1024 + tid * 4;
    float4 a = *(const float4*)(tmp + base);
    float4 r = *(const float4*)(xln + base);
    float x0 = a.x + r.x, x1 = a.y + r.y, x2 = a.z + r.z, x3 = a.w + r.w;
    float s1 = x0 + x1 + x2 + x3;
    float s2 = x0*x0 + x1*x1 + x2*x2 + x3*x3;
#pragma unroll
    for (int off = 1; off < 64; off <<= 1) { s1 += __shfl_xor(s1, off); s2 += __shfl_xor(s2, off); }
    __shared__ float red[8];
    if ((tid & 63) == 0) { int w = tid >> 6; red[w] = s1; red[4 + w] = s2; }
    __syncthreads();
    s1 = red[0] + red[1] + red[2] + red[3];
    s2 = red[4] + red[5] + red[6] + red[7];
    float m = s1 * (1.f / 1024.f);
    float var = s2 * (1.f / 1024.f) - m * m;
    float inv = rsqrtf(var + 1e-5f);
    int c = tid * 4;
    out[base + 0] = (x0 - m) * inv * g[c+0] + be[c+0];
    out[base + 1] = (x1 - m) * inv * g[c+1] + be[c+1];
    out[base + 2] = (x2 - m) * inv * g[c+2] + be[c+2];
    out[base + 3] = (x3 - m) * inv * g[c+3] + be[c+3];
}

// ---------------------------------------------------------------------------
// Classifier: logits[bn][c] = attn_out[bn] . Wc[:,c] + bc[c]
// ---------------------------------------------------------------------------
__global__ __launch_bounds__(256)
void classify_kernel(const float* __restrict__ x, const float* __restrict__ Wc,
                     const float* __restrict__ bc, float* __restrict__ out)
{
    const int bn = blockIdx.x;
    const int tid = threadIdx.x;
    const float* row = x + (size_t)bn * 1024;
    float a0 = 0.f, a1 = 0.f, a2 = 0.f;
    for (int kk = tid; kk < 1024; kk += 256) {
        float xv = row[kk];
        a0 = fmaf(xv, Wc[kk * 3 + 0], a0);
        a1 = fmaf(xv, Wc[kk * 3 + 1], a1);
        a2 = fmaf(xv, Wc[kk * 3 + 2], a2);
    }
#pragma unroll
    for (int off = 1; off < 64; off <<= 1) {
        a0 += __shfl_xor(a0, off); a1 += __shfl_xor(a1, off); a2 += __shfl_xor(a2, off);
    }
    __shared__ float red[12];
    if ((tid & 63) == 0) { int w = tid >> 6; red[w*3] = a0; red[w*3+1] = a1; red[w*3+2] = a2; }
    __syncthreads();
    if (tid == 0) {
        out[bn * 3 + 0] = red[0] + red[3] + red[6] + red[9]  + bc[0];
        out[bn * 3 + 1] = red[1] + red[4] + red[7] + red[10] + bc[1];
        out[bn * 3 + 2] = red[2] + red[5] + red[8] + red[11] + bc[2];
    }
}

// ---------------------------------------------------------------------------
// Workspace layout (bytes)
// ---------------------------------------------------------------------------
#define OFF_PREF 0ull                    // bf16 [2048][8][2048]  = 64 MiB
#define OFF_PREB 67108864ull             // bf16 same
#define OFF_SEQ  134217728ull            // bf16 [8][2048][1024]  = 32 MiB
#define OFF_XLN  167772160ull            // f32  [256][1024]
#define OFF_Q    168820736ull
#define OFF_K    169869312ull
#define OFF_V    170917888ull
#define OFF_CTX  171966464ull
#define OFF_TMP  173015040ull
#define OFF_ATT  174063616ull
#define OFF_HBUF 175112192ull            // f32 [2][2][NREP][4096] = 256 KiB
#define OFF_SYNC 175374336ull            // int flags [2][NREP][64][32] = 64 KiB

extern "C" void kernel_launch(void* const* d_in, const int* in_sizes, int n_in,
                              void* d_out, int out_size, void* d_ws, size_t ws_size,
                              hipStream_t stream)
{
    const float* enc   = (const float*)d_in[0];
    const int*   heads = (const int*)d_in[1];
    const int*   tails = (const int*)d_in[2];
    const float* amask = (const float*)d_in[3];
    const float* Wih_f = (const float*)d_in[4];
    const float* Whh_f = (const float*)d_in[5];
    const float* b_f   = (const float*)d_in[6];
    const float* Wih_b = (const float*)d_in[7];
    const float* Whh_b = (const float*)d_in[8];
    const float* b_b   = (const float*)d_in[9];
    const float* ln_g  = (const float*)d_in[10];
    const float* ln_b  = (const float*)d_in[11];
    const float* Wq    = (const float*)d_in[12];
    const float* bq    = (const float*)d_in[13];
    const float* Wk    = (const float*)d_in[14];
    const float* bk    = (const float*)d_in[15];
    const float* Wv    = (const float*)d_in[16];
    const float* bv    = (const float*)d_in[17];
    const float* dist  = (const float*)d_in[18];
    const float* Wo    = (const float*)d_in[19];
    const float* bo    = (const float*)d_in[20];
    const float* ao_g  = (const float*)d_in[21];
    const float* ao_b  = (const float*)d_in[22];
    const float* Wc    = (const float*)d_in[23];
    const float* bc    = (const float*)d_in[24];

    char* ws = (char*)d_ws;
    unsigned short* pre_f = (unsigned short*)(ws + OFF_PREF);
    unsigned short* pre_b = (unsigned short*)(ws + OFF_PREB);
    unsigned short* seqp  = (unsigned short*)(ws + OFF_SEQ);
    float* xlnp = (float*)(ws + OFF_XLN);
    float* qb   = (float*)(ws + OFF_Q);
    float* kb   = (float*)(ws + OFF_K);
    float* vb   = (float*)(ws + OFF_V);
    float* ctxb = (float*)(ws + OFF_CTX);
    float* tmpb = (float*)(ws + OFF_TMP);
    float* attb = (float*)(ws + OFF_ATT);
    float* hbuf = (float*)(ws + OFF_HBUF);
    int*   flags = (int*)(ws + OFF_SYNC);

    // zero h0 exchange buffers + step flags (ws is poisoned 0xAA)
    hipMemsetAsync(ws + OFF_HBUF, 0, 262144 + 65536, stream);

    // 1) LSTM input projections: pre = enc @ Wih^T + b   (both directions)
    gemm_f32<1, 1, 1><<<dim3(16, 128), 256, 0, stream>>>(enc, Wih_f, b_f, pre_f, 16384, 2048, 1024);
    gemm_f32<1, 1, 1><<<dim3(16, 128), 256, 0, stream>>>(enc, Wih_b, b_b, pre_b, 16384, 2048, 1024);

    // 2) Serial BiLSTM recurrence (persistent, flag-synced, NREP-replicated)
    lstm_rec_kernel<<<128, 256, 0, stream>>>(pre_f, pre_b, Whh_f, Whh_b, hbuf, flags, seqp);

    // 3) Span mean pooling + LayerNorm
    pool_ln_kernel<<<256, 256, 0, stream>>>(seqp, heads, tails, ln_g, ln_b, xlnp);

    // 4) q,k,v projections
    gemm_f32<0, 0, 0><<<dim3(8, 2), 256, 0, stream>>>(xlnp, Wq, bq, qb, 256, 1024, 1024);
    gemm_f32<0, 0, 0><<<dim3(8, 2), 256, 0, stream>>>(xlnp, Wk, bk, kb, 256, 1024, 1024);
    gemm_f32<0, 0, 0><<<dim3(8, 2), 256, 0, stream>>>(xlnp, Wv, bv, vb, 256, 1024, 1024);

    // 5) relative-key attention
    attn_kernel<<<128, 256, 0, stream>>>(qb, kb, vb, dist, amask, ctxb);

    // 6) output projection + residual LN
    gemm_f32<0, 0, 0><<<dim3(8, 2), 256, 0, stream>>>(ctxb, Wo, bo, tmpb, 256, 1024, 1024);
    resid_ln_kernel<<<256, 256, 0, stream>>>(tmpb, xlnp, ao_g, ao_b, attb);

    // 7) classifier -> d_out [8,32,3] f32
    classify_kernel<<<256, 256, 0, stream>>>(attb, Wc, bc, (float*)d_out);
}